// Round 19
// baseline (417.117 us; speedup 1.0000x reference)
//
#include <hip/hip_runtime.h>

// B=4, S=2048, D=512, H=8, DK=DV=64
typedef __attribute__((ext_vector_type(8))) short short8;
typedef __attribute__((ext_vector_type(4))) float f32x4;
typedef __attribute__((ext_vector_type(16))) float f32x16;

__device__ __forceinline__ short f2bf(float f) {
  union { float f; unsigned u; } x; x.f = f;
  return (short)((x.u + 0x7FFFu + ((x.u >> 16) & 1u)) >> 16);
}
__device__ __forceinline__ unsigned pk2(float a, float b) {
  return (unsigned)(unsigned short)f2bf(a) | ((unsigned)(unsigned short)f2bf(b) << 16);
}

#define LDS_BARRIER() do { \
  asm volatile("s_waitcnt lgkmcnt(0)" ::: "memory"); \
  __builtin_amdgcn_s_barrier(); \
} while (0)

// Wt[m][n][k] = W_m[k][n], bf16  (3 x 512 x 512)
__global__ __launch_bounds__(256) void prep_wt_k(const float* __restrict__ Wq,
    const float* __restrict__ Wk, const float* __restrict__ Wv,
    short* __restrict__ wt) {
  int idx = blockIdx.x * 256 + threadIdx.x;
  int m = idx >> 18;
  int r = idx & 0x3FFFF;
  int k = r >> 9, n = r & 511;
  const float* W = (m == 0) ? Wq : (m == 1) ? Wk : Wv;
  wt[(m << 18) + (n << 9) + k] = f2bf(W[(k << 9) + n]);
}

// convert q,k,v f32 -> bf16 [3][8192][512]
__global__ __launch_bounds__(256) void xcvt_k(const float* __restrict__ q,
    const float* __restrict__ k_, const float* __restrict__ v,
    short* __restrict__ xb) {
  int i = blockIdx.x * 256 + threadIdx.x;
  int m = i >> 19;
  int r = i & 0x7FFFF;
  const float* X = (m == 0) ? q : (m == 1) ? k_ : v;
  float4 f0 = ((const float4*)X)[2 * r];
  float4 f1 = ((const float4*)X)[2 * r + 1];
  short8 t;
  t[0] = f2bf(f0.x); t[1] = f2bf(f0.y); t[2] = f2bf(f0.z); t[3] = f2bf(f0.w);
  t[4] = f2bf(f1.x); t[5] = f2bf(f1.y); t[6] = f2bf(f1.z); t[7] = f2bf(f1.w);
  *(short8*)(xb + (size_t)i * 8) = t;
}

// X[8192][512] @ Wt[n][k] -> qh [b][h][s][64], kh row-permuted for 32x32 MFMA,
// vt [b][h][dv][s]
template<int BF>
__global__ __launch_bounds__(64) void proj_k(const float* __restrict__ q,
    const float* __restrict__ k_, const float* __restrict__ v,
    const short* __restrict__ xb, const short* __restrict__ wt,
    short* __restrict__ qh, short* __restrict__ kh, short* __restrict__ vt) {
  int bid = blockIdx.x;
  int mat = bid >> 10;
  int t = bid & 1023;
  int tm = t >> 3, tn = t & 7;
  const float* X = (mat == 0) ? q : (mat == 1) ? k_ : v;
  const short* Xb = xb + ((size_t)mat << 22);
  const short* W = wt + ((size_t)mat << 18);
  int lane = threadIdx.x;
  int lr = lane & 15, lg = lane >> 4;
  int m0 = tm << 6, n0 = tn << 6;
  f32x4 acc[4][4];
  #pragma unroll
  for (int i = 0; i < 4; i++)
    #pragma unroll
    for (int j = 0; j < 4; j++) acc[i][j] = (f32x4){0.f, 0.f, 0.f, 0.f};
  for (int k0 = 0; k0 < 512; k0 += 32) {
    short8 a[4], bfr[4];
    #pragma unroll
    for (int i = 0; i < 4; i++) {
      if (BF) {
        a[i] = *(const short8*)(Xb + (size_t)(m0 + 16 * i + lr) * 512 + k0 + 8 * lg);
      } else {
        const float* p = X + (size_t)(m0 + 16 * i + lr) * 512 + k0 + 8 * lg;
        float4 f0 = *(const float4*)p;
        float4 f1 = *(const float4*)(p + 4);
        short8 tt;
        tt[0] = f2bf(f0.x); tt[1] = f2bf(f0.y); tt[2] = f2bf(f0.z); tt[3] = f2bf(f0.w);
        tt[4] = f2bf(f1.x); tt[5] = f2bf(f1.y); tt[6] = f2bf(f1.z); tt[7] = f2bf(f1.w);
        a[i] = tt;
      }
    }
    #pragma unroll
    for (int j = 0; j < 4; j++)
      bfr[j] = *(const short8*)(W + (size_t)(n0 + 16 * j + lr) * 512 + k0 + 8 * lg);
    #pragma unroll
    for (int i = 0; i < 4; i++)
      #pragma unroll
      for (int j = 0; j < 4; j++)
        acc[i][j] = __builtin_amdgcn_mfma_f32_16x16x32_bf16(a[i], bfr[j], acc[i][j], 0, 0, 0);
  }
  #pragma unroll
  for (int i = 0; i < 4; i++)
    #pragma unroll
    for (int j = 0; j < 4; j++)
      #pragma unroll
      for (int r = 0; r < 4; r++) {
        int row = m0 + 16 * i + lg * 4 + r;
        int col = n0 + 16 * j + lr;
        int bb = row >> 11, s = row & 2047;
        int h = col >> 6, d = col & 63;
        short val = f2bf(acc[i][j][r]);
        if (mat == 0) {
          qh[((size_t)((bb * 8 + h) * 2048 + s) << 6) + d] = val;
        } else if (mat == 1) {
          // 32x32-MFMA row permutation: within 32-block, k=16h+j -> slot
          // (j&3)+8*(j>>2)+4h
          int o = s & 31, hb = o >> 4, j = o & 15;
          int loc = (j & 3) + ((j >> 2) << 3) + (hb << 2);
          int sp = (s & ~31) | loc;
          kh[((size_t)((bb * 8 + h) * 2048 + sp) << 6) + d] = val;
        } else {
          vt[((size_t)((bb * 8 + h) * 64 + d) << 11) + s] = val;
        }
      }
}

__device__ __forceinline__ float eterm(float s, float m, float cs, float gl2, float sh2) {
  return __builtin_amdgcn_exp2f(fmaf(s, cs, fmaf(m, gl2, -sh2)));
}

// Block = one (b,h) x 256 q-rows (8 waves x 32 rows, 32x32 MFMA). K/V staged
// per 64-col tile into LDS (XOR-swizzled, dbuf, depth-2 reg prefetch);
// lgkmcnt-only barriers; direct f32 P stores. Grid 256 -> 1 block/CU, 16 w/CU.
__global__ __launch_bounds__(512, 4) void attn_k(const short* __restrict__ qh,
    const short* __restrict__ kh, const short* __restrict__ vt,
    const float* __restrict__ mask, const float* __restrict__ gamma_p,
    float* __restrict__ out, float* __restrict__ attn_out) {
  __shared__ __align__(16) short Kl[2][4096];          // 2 x 8 KB (64 rows x 64 sh)
  __shared__ __align__(16) short Vl[2][4096];          // 2 x 8 KB

  int bid = blockIdx.x;
  int work = ((bid & 7) << 5) + (bid >> 3);   // XCD-bijective: 8 x 32
  int bh = work >> 3;
  int qt = work & 7;
  int q0 = qt << 8;                           // 256 q-rows per block
  int bb = bh >> 3, hd = bh & 7;
  int tid = threadIdx.x;
  int w = tid >> 6, lane = tid & 63;
  int ql = lane & 31, hh = lane >> 5;
  int qw2 = q0 + (w << 5);
  int qg2 = qw2 + ql;

  const short* Kb = kh + (size_t)bh * (2048 * 64);
  const short* Qb = qh + (size_t)bh * (2048 * 64);
  const short* Vb = vt + (size_t)bh * (64 * 2048);
  const float* Mrow = mask + (size_t)bb * (2048 * 2048) + (size_t)qg2 * 2048 + (hh << 4);
  float* Ap = attn_out + ((size_t)bh * 2048 + qg2) * 2048 + (hh << 4);

  const float LOG2E = 1.4426950408889634f;
  float gamma = gamma_p[0];
  float shift = fmaxf(gamma, 0.f) + 16.0f;
  float cs = 0.125f * LOG2E;
  float gl2 = gamma * LOG2E;
  float sh2 = shift * LOG2E;

  // staging: 512 threads, each stages 16B of K tile and 16B of V tile
  int srow = tid >> 3;                        // row 0..63
  int u0 = tid & 7;                           // 16B unit 0..7
  int sd = srow * 64 + ((u0 ^ (srow & 7)) << 3);
  const short* Kg = Kb + (size_t)srow * 64 + (u0 << 3);      // + t*4096
  const short* Vg = Vb + (size_t)srow * 2048 + (u0 << 3);    // + t*64

  short8 qf[4];
  #pragma unroll
  for (int f = 0; f < 4; ++f)
    qf[f] = *(const short8*)(Qb + (size_t)qg2 * 64 + f * 16 + (hh << 3));

  #define LDK32(cu, row, u) (*(const short8*)&Kl[cu][(row) * 64 + ((((u) ^ ((row) & 7))) << 3)])
  #define LDV32(cu, row, u) (*(const short8*)&Vl[cu][(row) * 64 + ((((u) ^ ((row) & 7))) << 3)])

  // ================= pass A: row sums =================
  float lsum = 0.f;
  {
    short8 rk = *(const short8*)(Kg);
    *(short8*)&Kl[0][sd] = rk;
    rk = *(const short8*)(Kg + 4096);
    LDS_BARRIER();
    for (int t = 0; t < 32; ++t) {
      int cu = t & 1, nx = cu ^ 1;
      if (t < 31) *(short8*)&Kl[nx][sd] = rk;
      if (t < 30) rk = *(const short8*)(Kg + (size_t)(t + 2) * 4096);
      #pragma unroll
      for (int mb = 0; mb < 2; ++mb) {
        float4 mk0 = *(const float4*)(Mrow + (t << 6) + (mb << 5));
        float4 mk1 = *(const float4*)(Mrow + (t << 6) + (mb << 5) + 4);
        float4 mk2 = *(const float4*)(Mrow + (t << 6) + (mb << 5) + 8);
        float4 mk3 = *(const float4*)(Mrow + (t << 6) + (mb << 5) + 12);
        f32x16 S = (f32x16){0.f,0.f,0.f,0.f,0.f,0.f,0.f,0.f,
                            0.f,0.f,0.f,0.f,0.f,0.f,0.f,0.f};
        #pragma unroll
        for (int d4 = 0; d4 < 4; ++d4) {
          short8 kf = LDK32(cu, (mb << 5) + ql, (d4 << 1) + hh);
          S = __builtin_amdgcn_mfma_f32_32x32x16_bf16(kf, qf[d4], S, 0, 0, 0);
        }
        lsum += eterm(S[0],  mk0.x, cs, gl2, sh2);
        lsum += eterm(S[1],  mk0.y, cs, gl2, sh2);
        lsum += eterm(S[2],  mk0.z, cs, gl2, sh2);
        lsum += eterm(S[3],  mk0.w, cs, gl2, sh2);
        lsum += eterm(S[4],  mk1.x, cs, gl2, sh2);
        lsum += eterm(S[5],  mk1.y, cs, gl2, sh2);
        lsum += eterm(S[6],  mk1.z, cs, gl2, sh2);
        lsum += eterm(S[7],  mk1.w, cs, gl2, sh2);
        lsum += eterm(S[8],  mk2.x, cs, gl2, sh2);
        lsum += eterm(S[9],  mk2.y, cs, gl2, sh2);
        lsum += eterm(S[10], mk2.z, cs, gl2, sh2);
        lsum += eterm(S[11], mk2.w, cs, gl2, sh2);
        lsum += eterm(S[12], mk3.x, cs, gl2, sh2);
        lsum += eterm(S[13], mk3.y, cs, gl2, sh2);
        lsum += eterm(S[14], mk3.z, cs, gl2, sh2);
        lsum += eterm(S[15], mk3.w, cs, gl2, sh2);
      }
      LDS_BARRIER();
    }
  }
  lsum += __shfl_xor(lsum, 32);
  float inv = 1.0f / lsum;

  // ================= pass B =================
  f32x16 oacc[2];
  #pragma unroll
  for (int g = 0; g < 2; ++g)
    oacc[g] = (f32x16){0.f,0.f,0.f,0.f,0.f,0.f,0.f,0.f,
                       0.f,0.f,0.f,0.f,0.f,0.f,0.f,0.f};

  {
    short8 rk = *(const short8*)(Kg);
    short8 rv = *(const short8*)(Vg);
    *(short8*)&Kl[0][sd] = rk;
    *(short8*)&Vl[0][sd] = rv;
    rk = *(const short8*)(Kg + 4096);
    rv = *(const short8*)(Vg + 64);
    LDS_BARRIER();
    for (int t = 0; t < 32; ++t) {
      int cu = t & 1, nx = cu ^ 1;
      if (t < 31) {
        *(short8*)&Kl[nx][sd] = rk;
        *(short8*)&Vl[nx][sd] = rv;
      }
      if (t < 30) {
        rk = *(const short8*)(Kg + (size_t)(t + 2) * 4096);
        rv = *(const short8*)(Vg + (size_t)(t + 2) * 64);
      }
      #pragma unroll
      for (int mb = 0; mb < 2; ++mb) {
        float4 mk0 = *(const float4*)(Mrow + (t << 6) + (mb << 5));
        float4 mk1 = *(const float4*)(Mrow + (t << 6) + (mb << 5) + 4);
        float4 mk2 = *(const float4*)(Mrow + (t << 6) + (mb << 5) + 8);
        float4 mk3 = *(const float4*)(Mrow + (t << 6) + (mb << 5) + 12);
        f32x16 S = (f32x16){0.f,0.f,0.f,0.f,0.f,0.f,0.f,0.f,
                            0.f,0.f,0.f,0.f,0.f,0.f,0.f,0.f};
        #pragma unroll
        for (int d4 = 0; d4 < 4; ++d4) {
          short8 kf = LDK32(cu, (mb << 5) + ql, (d4 << 1) + hh);
          S = __builtin_amdgcn_mfma_f32_32x32x16_bf16(kf, qf[d4], S, 0, 0, 0);
        }
        float p[16];
        p[0]  = eterm(S[0],  mk0.x, cs, gl2, sh2) * inv;
        p[1]  = eterm(S[1],  mk0.y, cs, gl2, sh2) * inv;
        p[2]  = eterm(S[2],  mk0.z, cs, gl2, sh2) * inv;
        p[3]  = eterm(S[3],  mk0.w, cs, gl2, sh2) * inv;
        p[4]  = eterm(S[4],  mk1.x, cs, gl2, sh2) * inv;
        p[5]  = eterm(S[5],  mk1.y, cs, gl2, sh2) * inv;
        p[6]  = eterm(S[6],  mk1.z, cs, gl2, sh2) * inv;
        p[7]  = eterm(S[7],  mk1.w, cs, gl2, sh2) * inv;
        p[8]  = eterm(S[8],  mk2.x, cs, gl2, sh2) * inv;
        p[9]  = eterm(S[9],  mk2.y, cs, gl2, sh2) * inv;
        p[10] = eterm(S[10], mk2.z, cs, gl2, sh2) * inv;
        p[11] = eterm(S[11], mk2.w, cs, gl2, sh2) * inv;
        p[12] = eterm(S[12], mk3.x, cs, gl2, sh2) * inv;
        p[13] = eterm(S[13], mk3.y, cs, gl2, sh2) * inv;
        p[14] = eterm(S[14], mk3.z, cs, gl2, sh2) * inv;
        p[15] = eterm(S[15], mk3.w, cs, gl2, sh2) * inv;
        *(f32x4*)(Ap + (t << 6) + (mb << 5))      = (f32x4){p[0],  p[1],  p[2],  p[3]};
        *(f32x4*)(Ap + (t << 6) + (mb << 5) + 4)  = (f32x4){p[4],  p[5],  p[6],  p[7]};
        *(f32x4*)(Ap + (t << 6) + (mb << 5) + 8)  = (f32x4){p[8],  p[9],  p[10], p[11]};
        *(f32x4*)(Ap + (t << 6) + (mb << 5) + 12) = (f32x4){p[12], p[13], p[14], p[15]};
        #pragma unroll
        for (int c = 0; c < 2; ++c) {
          union { unsigned u4[4]; short8 s8; } pa;
          pa.u4[0] = pk2(p[c * 8 + 0], p[c * 8 + 1]);
          pa.u4[1] = pk2(p[c * 8 + 2], p[c * 8 + 3]);
          pa.u4[2] = pk2(p[c * 8 + 4], p[c * 8 + 5]);
          pa.u4[3] = pk2(p[c * 8 + 6], p[c * 8 + 7]);
          #pragma unroll
          for (int g = 0; g < 2; ++g) {
            short8 vf = LDV32(cu, (g << 5) + ql, (mb << 2) + c + (hh << 1));
            oacc[g] = __builtin_amdgcn_mfma_f32_32x32x16_bf16(pa.s8, vf, oacc[g], 0, 0, 0);
          }
        }
      }
      LDS_BARRIER();
    }
  }

  #pragma unroll
  for (int g = 0; g < 2; ++g)
    #pragma unroll
    for (int r = 0; r < 16; ++r) {
      int qrow = (r & 3) + ((r >> 2) << 3) + (hh << 2);
      out[((size_t)(bb * 2048) + qw2 + qrow) * 512 + (hd << 6) + (g << 5) + ql] = oacc[g][r];
    }
  #undef LDK32
  #undef LDV32
}

extern "C" void kernel_launch(void* const* d_in, const int* in_sizes, int n_in,
                              void* d_out, int out_size, void* d_ws, size_t ws_size,
                              hipStream_t stream) {
  const float* q    = (const float*)d_in[0];
  const float* k    = (const float*)d_in[1];
  const float* v    = (const float*)d_in[2];
  const float* mask = (const float*)d_in[3];
  const float* Wq   = (const float*)d_in[4];
  const float* Wk   = (const float*)d_in[5];
  const float* Wv   = (const float*)d_in[6];
  const float* gma  = (const float*)d_in[7];
  float* out = (float*)d_out;
  float* attn_out = out + (size_t)4 * 2048 * 512;

  short* wt = (short*)d_ws;                              // 1.5 MB
  short* qh = (short*)((char*)d_ws + (2u << 20));        // 8 MB
  short* kh = qh + (size_t)4 * 8 * 2048 * 64;            // 8 MB (row-permuted)
  short* vt = kh + (size_t)4 * 8 * 2048 * 64;            // 8 MB
  short* xb = vt + (size_t)4 * 8 * 2048 * 64;            // 24 MB (optional)
  bool big_ws = ws_size >= (size_t)(50u << 20);

  hipLaunchKernelGGL(prep_wt_k, dim3(3072), dim3(256), 0, stream, Wq, Wk, Wv, wt);
  if (big_ws) {
    hipLaunchKernelGGL(xcvt_k, dim3(6144), dim3(256), 0, stream, q, k, v, xb);
    hipLaunchKernelGGL(proj_k<1>, dim3(3072), dim3(64), 0, stream, q, k, v, xb, wt, qh, kh, vt);
  } else {
    hipLaunchKernelGGL(proj_k<0>, dim3(3072), dim3(64), 0, stream, q, k, v, xb, wt, qh, kh, vt);
  }
  hipLaunchKernelGGL(attn_k, dim3(256), dim3(512), 0, stream, qh, kh, vt, mask, gma,
                     out, attn_out);
}

// Round 20
// 339.076 us; speedup vs baseline: 1.2302x; 1.2302x over previous
//
#include <hip/hip_runtime.h>

// B=4, S=2048, D=512, H=8, DK=DV=64
typedef __attribute__((ext_vector_type(8))) short short8;
typedef __attribute__((ext_vector_type(4))) float f32x4;

__device__ __forceinline__ short f2bf(float f) {
  union { float f; unsigned u; } x; x.f = f;
  return (short)((x.u + 0x7FFFu + ((x.u >> 16) & 1u)) >> 16);
}
__device__ __forceinline__ unsigned pk2(float a, float b) {
  return (unsigned)(unsigned short)f2bf(a) | ((unsigned)(unsigned short)f2bf(b) << 16);
}

// lgkmcnt-only barrier: LDS visibility without draining global loads/stores.
#define LDS_BARRIER() do { \
  asm volatile("s_waitcnt lgkmcnt(0)" ::: "memory"); \
  __builtin_amdgcn_s_barrier(); \
} while (0)

// Wt[m][n][k] = W_m[k][n], bf16  (3 x 512 x 512)
__global__ __launch_bounds__(256) void prep_wt_k(const float* __restrict__ Wq,
    const float* __restrict__ Wk, const float* __restrict__ Wv,
    short* __restrict__ wt) {
  int idx = blockIdx.x * 256 + threadIdx.x;
  int m = idx >> 18;
  int r = idx & 0x3FFFF;
  int k = r >> 9, n = r & 511;
  const float* W = (m == 0) ? Wq : (m == 1) ? Wk : Wv;
  wt[(m << 18) + (n << 9) + k] = f2bf(W[(k << 9) + n]);
}

// convert q,k,v f32 -> bf16 [3][8192][512]
__global__ __launch_bounds__(256) void xcvt_k(const float* __restrict__ q,
    const float* __restrict__ k_, const float* __restrict__ v,
    short* __restrict__ xb) {
  int i = blockIdx.x * 256 + threadIdx.x;
  int m = i >> 19;
  int r = i & 0x7FFFF;
  const float* X = (m == 0) ? q : (m == 1) ? k_ : v;
  float4 f0 = ((const float4*)X)[2 * r];
  float4 f1 = ((const float4*)X)[2 * r + 1];
  short8 t;
  t[0] = f2bf(f0.x); t[1] = f2bf(f0.y); t[2] = f2bf(f0.z); t[3] = f2bf(f0.w);
  t[4] = f2bf(f1.x); t[5] = f2bf(f1.y); t[6] = f2bf(f1.z); t[7] = f2bf(f1.w);
  *(short8*)(xb + (size_t)i * 8) = t;
}

// X[8192][512] @ Wt[n][k] -> qh [b][h][s][64], kh row-permuted, vt [b][h][dv][s]
template<int BF>
__global__ __launch_bounds__(64) void proj_k(const float* __restrict__ q,
    const float* __restrict__ k_, const float* __restrict__ v,
    const short* __restrict__ xb, const short* __restrict__ wt,
    short* __restrict__ qh, short* __restrict__ kh, short* __restrict__ vt) {
  int bid = blockIdx.x;
  int mat = bid >> 10;
  int t = bid & 1023;
  int tm = t >> 3, tn = t & 7;
  const float* X = (mat == 0) ? q : (mat == 1) ? k_ : v;
  const short* Xb = xb + ((size_t)mat << 22);
  const short* W = wt + ((size_t)mat << 18);
  int lane = threadIdx.x;
  int lr = lane & 15, lg = lane >> 4;
  int m0 = tm << 6, n0 = tn << 6;
  f32x4 acc[4][4];
  #pragma unroll
  for (int i = 0; i < 4; i++)
    #pragma unroll
    for (int j = 0; j < 4; j++) acc[i][j] = (f32x4){0.f, 0.f, 0.f, 0.f};
  for (int k0 = 0; k0 < 512; k0 += 32) {
    short8 a[4], bfr[4];
    #pragma unroll
    for (int i = 0; i < 4; i++) {
      if (BF) {
        a[i] = *(const short8*)(Xb + (size_t)(m0 + 16 * i + lr) * 512 + k0 + 8 * lg);
      } else {
        const float* p = X + (size_t)(m0 + 16 * i + lr) * 512 + k0 + 8 * lg;
        float4 f0 = *(const float4*)p;
        float4 f1 = *(const float4*)(p + 4);
        short8 tt;
        tt[0] = f2bf(f0.x); tt[1] = f2bf(f0.y); tt[2] = f2bf(f0.z); tt[3] = f2bf(f0.w);
        tt[4] = f2bf(f1.x); tt[5] = f2bf(f1.y); tt[6] = f2bf(f1.z); tt[7] = f2bf(f1.w);
        a[i] = tt;
      }
    }
    #pragma unroll
    for (int j = 0; j < 4; j++)
      bfr[j] = *(const short8*)(W + (size_t)(n0 + 16 * j + lr) * 512 + k0 + 8 * lg);
    #pragma unroll
    for (int i = 0; i < 4; i++)
      #pragma unroll
      for (int j = 0; j < 4; j++)
        acc[i][j] = __builtin_amdgcn_mfma_f32_16x16x32_bf16(a[i], bfr[j], acc[i][j], 0, 0, 0);
  }
  #pragma unroll
  for (int i = 0; i < 4; i++)
    #pragma unroll
    for (int j = 0; j < 4; j++)
      #pragma unroll
      for (int r = 0; r < 4; r++) {
        int row = m0 + 16 * i + lg * 4 + r;
        int col = n0 + 16 * j + lr;
        int bb = row >> 11, s = row & 2047;
        int h = col >> 6, d = col & 63;
        short val = f2bf(acc[i][j][r]);
        if (mat == 0) {
          qh[((size_t)((bb * 8 + h) * 2048 + s) << 6) + d] = val;
        } else if (mat == 1) {
          int o = s & 31, aa = o >> 3, b7 = o & 7;
          int loc = (b7 < 4) ? ((aa << 2) | b7) : (16 + ((aa << 2) | (b7 - 4)));
          int sp = (s & ~31) | loc;
          kh[((size_t)((bb * 8 + h) * 2048 + sp) << 6) + d] = val;
        } else {
          vt[((size_t)((bb * 8 + h) * 64 + d) << 11) + s] = val;
        }
      }
}

__device__ __forceinline__ float eterm(float s, float m, float cs, float gl2, float sh2) {
  return __builtin_amdgcn_exp2f(fmaf(s, cs, fmaf(m, gl2, -sh2)));
}

// Block = one (b,h) x 128 q-rows (8 waves x 16 rows). K/V staged per 64-col tile
// into LDS (XOR-swizzled, dbuf); depth-2 register prefetch; lgkmcnt-only
// barriers. P written DIRECTLY to attn_out as f32 (no LDS round-trip).
// launch_bounds (512,4): VGPR budget 128 so prefetch registers survive.
__global__ __launch_bounds__(512, 4) void attn_k(const short* __restrict__ qh,
    const short* __restrict__ kh, const short* __restrict__ vt,
    const float* __restrict__ mask, const float* __restrict__ gamma_p,
    float* __restrict__ out, float* __restrict__ attn_out) {
  __shared__ __align__(16) short Kl[2][4096];          // 2 x 8 KB
  __shared__ __align__(16) short Vl[2][4096];          // 2 x 8 KB

  int bid = blockIdx.x;
  int work = ((bid & 7) << 6) + (bid >> 3);   // XCD-bijective: 8 x 64
  int bh = work >> 4;
  int qt = work & 15;
  int q0 = qt << 7;
  int bb = bh >> 3, h = bh & 7;
  int tid = threadIdx.x;
  int w = tid >> 6, lane = tid & 63, lr = lane & 15, lg = lane >> 4;
  int qw = q0 + (w << 4);
  int qg = qw + lr;

  const short* Kb = kh + (size_t)bh * (2048 * 64);
  const short* Qb = qh + (size_t)bh * (2048 * 64);
  const short* Vb = vt + (size_t)bh * (64 * 2048);
  const float* Mrow = mask + (size_t)bb * (2048 * 2048) + (size_t)qg * 2048 + (lg << 3);
  float* Ap = attn_out + (size_t)bh * (2048 * 2048) + (size_t)qg * 2048 + (lg << 3);

  const float LOG2E = 1.4426950408889634f;
  float gamma = gamma_p[0];
  float shift = fmaxf(gamma, 0.f) + 16.0f;
  float cs = 0.125f * LOG2E;
  float gl2 = gamma * LOG2E;
  float sh2 = shift * LOG2E;

  // staging assignment: thread stages 16B of K tile and 16B of V tile
  int sr = tid >> 3;
  int sb = (tid & 7) << 4;
  int sdst = sr * 64 + (((sb) ^ ((sr & 7) << 4)) >> 1);
  const short* Kg = Kb + (size_t)tid * 8;                       // + t*4096
  const short* Vg = Vb + (size_t)sr * 2048 + ((tid & 7) << 3);  // + t*64

  short8 qf0 = *(const short8*)(Qb + (size_t)qg * 64 + 8 * lg);
  short8 qf1 = *(const short8*)(Qb + (size_t)qg * 64 + 32 + 8 * lg);

  #define LDK(cu, row, boff) (*(const short8*)&Kl[cu][(row) * 64 + ((((boff) ^ (((row) & 7) << 4))) >> 1)])
  #define LDV(cu, row, boff) (*(const short8*)&Vl[cu][(row) * 64 + ((((boff) ^ (((row) & 7) << 4))) >> 1)])

  // ================= pass A: row sums =================
  float lsum = 0.f;
  {
    short8 rk = *(const short8*)(Kg);
    *(short8*)&Kl[0][sdst] = rk;
    rk = *(const short8*)(Kg + 4096);           // tile 1
    float4 a0 = *(const float4*)(Mrow + 0);
    float4 a1 = *(const float4*)(Mrow + 4);
    float4 a2 = *(const float4*)(Mrow + 32);
    float4 a3 = *(const float4*)(Mrow + 36);
    LDS_BARRIER();
    for (int t = 0; t < 32; ++t) {
      int cu = t & 1, nx = cu ^ 1;
      int nc = ((t + 1) << 6) & 2047;
      float4 n0 = *(const float4*)(Mrow + nc);
      float4 n1 = *(const float4*)(Mrow + nc + 4);
      float4 n2 = *(const float4*)(Mrow + nc + 32);
      float4 n3 = *(const float4*)(Mrow + nc + 36);
      if (t < 31) *(short8*)&Kl[nx][sdst] = rk;       // data for t+1 (loaded at t-1)
      if (t < 30) rk = *(const short8*)(Kg + (size_t)(t + 2) * 4096);
      #pragma unroll
      for (int m = 0; m < 2; ++m) {
        int rA = (m << 5) + lr, rC = rA + 16;
        short8 kA = LDK(cu, rA, (lg << 4));
        short8 kB = LDK(cu, rA, 64 + (lg << 4));
        short8 kC = LDK(cu, rC, (lg << 4));
        short8 kD = LDK(cu, rC, 64 + (lg << 4));
        f32x4 s0 = (f32x4){0.f, 0.f, 0.f, 0.f};
        s0 = __builtin_amdgcn_mfma_f32_16x16x32_bf16(kA, qf0, s0, 0, 0, 0);
        s0 = __builtin_amdgcn_mfma_f32_16x16x32_bf16(kB, qf1, s0, 0, 0, 0);
        f32x4 s1 = (f32x4){0.f, 0.f, 0.f, 0.f};
        s1 = __builtin_amdgcn_mfma_f32_16x16x32_bf16(kC, qf0, s1, 0, 0, 0);
        s1 = __builtin_amdgcn_mfma_f32_16x16x32_bf16(kD, qf1, s1, 0, 0, 0);
        float4 ca0 = (m == 0) ? a0 : a2;
        float4 ca1 = (m == 0) ? a1 : a3;
        lsum += eterm(s0[0], ca0.x, cs, gl2, sh2);
        lsum += eterm(s0[1], ca0.y, cs, gl2, sh2);
        lsum += eterm(s0[2], ca0.z, cs, gl2, sh2);
        lsum += eterm(s0[3], ca0.w, cs, gl2, sh2);
        lsum += eterm(s1[0], ca1.x, cs, gl2, sh2);
        lsum += eterm(s1[1], ca1.y, cs, gl2, sh2);
        lsum += eterm(s1[2], ca1.z, cs, gl2, sh2);
        lsum += eterm(s1[3], ca1.w, cs, gl2, sh2);
      }
      a0 = n0; a1 = n1; a2 = n2; a3 = n3;
      LDS_BARRIER();
    }
  }
  lsum += __shfl_xor(lsum, 16);
  lsum += __shfl_xor(lsum, 32);
  float inv = 1.0f / lsum;

  // ================= pass B =================
  f32x4 oacc[4];
  #pragma unroll
  for (int j = 0; j < 4; j++) oacc[j] = (f32x4){0.f, 0.f, 0.f, 0.f};

  {
    short8 rk = *(const short8*)(Kg);
    short8 rv = *(const short8*)(Vg);
    *(short8*)&Kl[0][sdst] = rk;
    *(short8*)&Vl[0][sdst] = rv;
    rk = *(const short8*)(Kg + 4096);
    rv = *(const short8*)(Vg + 64);
    float4 a0 = *(const float4*)(Mrow + 0);
    float4 a1 = *(const float4*)(Mrow + 4);
    float4 a2 = *(const float4*)(Mrow + 32);
    float4 a3 = *(const float4*)(Mrow + 36);
    LDS_BARRIER();
    for (int t = 0; t < 32; ++t) {
      int cu = t & 1, nx = cu ^ 1;
      int nc = ((t + 1) << 6) & 2047;
      float4 n0 = *(const float4*)(Mrow + nc);
      float4 n1 = *(const float4*)(Mrow + nc + 4);
      float4 n2 = *(const float4*)(Mrow + nc + 32);
      float4 n3 = *(const float4*)(Mrow + nc + 36);
      if (t < 31) {
        *(short8*)&Kl[nx][sdst] = rk;
        *(short8*)&Vl[nx][sdst] = rv;
      }
      if (t < 30) {
        rk = *(const short8*)(Kg + (size_t)(t + 2) * 4096);
        rv = *(const short8*)(Vg + (size_t)(t + 2) * 64);
      }
      #pragma unroll
      for (int m = 0; m < 2; ++m) {
        int rA = (m << 5) + lr, rC = rA + 16;
        short8 kA = LDK(cu, rA, (lg << 4));
        short8 kB = LDK(cu, rA, 64 + (lg << 4));
        short8 kC = LDK(cu, rC, (lg << 4));
        short8 kD = LDK(cu, rC, 64 + (lg << 4));
        short8 v0 = LDV(cu, lr,      (m << 6) + (lg << 4));
        short8 v1 = LDV(cu, 16 + lr, (m << 6) + (lg << 4));
        short8 v2 = LDV(cu, 32 + lr, (m << 6) + (lg << 4));
        short8 v3 = LDV(cu, 48 + lr, (m << 6) + (lg << 4));
        f32x4 s0 = (f32x4){0.f, 0.f, 0.f, 0.f};
        s0 = __builtin_amdgcn_mfma_f32_16x16x32_bf16(kA, qf0, s0, 0, 0, 0);
        s0 = __builtin_amdgcn_mfma_f32_16x16x32_bf16(kB, qf1, s0, 0, 0, 0);
        f32x4 s1 = (f32x4){0.f, 0.f, 0.f, 0.f};
        s1 = __builtin_amdgcn_mfma_f32_16x16x32_bf16(kC, qf0, s1, 0, 0, 0);
        s1 = __builtin_amdgcn_mfma_f32_16x16x32_bf16(kD, qf1, s1, 0, 0, 0);
        float4 ca0 = (m == 0) ? a0 : a2;
        float4 ca1 = (m == 0) ? a1 : a3;
        float p00 = eterm(s0[0], ca0.x, cs, gl2, sh2) * inv;
        float p01 = eterm(s0[1], ca0.y, cs, gl2, sh2) * inv;
        float p02 = eterm(s0[2], ca0.z, cs, gl2, sh2) * inv;
        float p03 = eterm(s0[3], ca0.w, cs, gl2, sh2) * inv;
        float p10 = eterm(s1[0], ca1.x, cs, gl2, sh2) * inv;
        float p11 = eterm(s1[1], ca1.y, cs, gl2, sh2) * inv;
        float p12 = eterm(s1[2], ca1.z, cs, gl2, sh2) * inv;
        float p13 = eterm(s1[3], ca1.w, cs, gl2, sh2) * inv;
        // direct f32 stores: lane's 8 P values are contiguous cols (permuted K)
        f32x4 wlo = (f32x4){p00, p01, p02, p03};
        f32x4 whi = (f32x4){p10, p11, p12, p13};
        *(f32x4*)(Ap + (t << 6) + (m << 5)) = wlo;
        *(f32x4*)(Ap + (t << 6) + (m << 5) + 4) = whi;
        // PV A-fragment: same 8 values packed bf16
        union { unsigned u4[4]; short8 s8; } pu;
        pu.u4[0] = pk2(p00, p01);
        pu.u4[1] = pk2(p02, p03);
        pu.u4[2] = pk2(p10, p11);
        pu.u4[3] = pk2(p12, p13);
        oacc[0] = __builtin_amdgcn_mfma_f32_16x16x32_bf16(pu.s8, v0, oacc[0], 0, 0, 0);
        oacc[1] = __builtin_amdgcn_mfma_f32_16x16x32_bf16(pu.s8, v1, oacc[1], 0, 0, 0);
        oacc[2] = __builtin_amdgcn_mfma_f32_16x16x32_bf16(pu.s8, v2, oacc[2], 0, 0, 0);
        oacc[3] = __builtin_amdgcn_mfma_f32_16x16x32_bf16(pu.s8, v3, oacc[3], 0, 0, 0);
      }
      a0 = n0; a1 = n1; a2 = n2; a3 = n3;
      LDS_BARRIER();
    }
  }

  #pragma unroll
  for (int j = 0; j < 4; j++)
    #pragma unroll
    for (int r = 0; r < 4; r++) {
      int qq = qw + (lg << 2) + r;
      out[((size_t)(bb * 2048) + qq) * 512 + (h << 6) + (j << 4) + lr] = oacc[j][r];
    }
  #undef LDK
  #undef LDV
}

extern "C" void kernel_launch(void* const* d_in, const int* in_sizes, int n_in,
                              void* d_out, int out_size, void* d_ws, size_t ws_size,
                              hipStream_t stream) {
  const float* q    = (const float*)d_in[0];
  const float* k    = (const float*)d_in[1];
  const float* v    = (const float*)d_in[2];
  const float* mask = (const float*)d_in[3];
  const float* Wq   = (const float*)d_in[4];
  const float* Wk   = (const float*)d_in[5];
  const float* Wv   = (const float*)d_in[6];
  const float* gma  = (const float*)d_in[7];
  float* out = (float*)d_out;
  float* attn_out = out + (size_t)4 * 2048 * 512;

  short* wt = (short*)d_ws;                              // 1.5 MB
  short* qh = (short*)((char*)d_ws + (2u << 20));        // 8 MB
  short* kh = qh + (size_t)4 * 8 * 2048 * 64;            // 8 MB (row-permuted)
  short* vt = kh + (size_t)4 * 8 * 2048 * 64;            // 8 MB
  short* xb = vt + (size_t)4 * 8 * 2048 * 64;            // 24 MB (optional)
  bool big_ws = ws_size >= (size_t)(50u << 20);

  hipLaunchKernelGGL(prep_wt_k, dim3(3072), dim3(256), 0, stream, Wq, Wk, Wv, wt);
  if (big_ws) {
    hipLaunchKernelGGL(xcvt_k, dim3(6144), dim3(256), 0, stream, q, k, v, xb);
    hipLaunchKernelGGL(proj_k<1>, dim3(3072), dim3(64), 0, stream, q, k, v, xb, wt, qh, kh, vt);
  } else {
    hipLaunchKernelGGL(proj_k<0>, dim3(3072), dim3(64), 0, stream, q, k, v, xb, wt, qh, kh, vt);
  }
  hipLaunchKernelGGL(attn_k, dim3(512), dim3(512), 0, stream, qh, kh, vt, mask, gma,
                     out, attn_out);
}